// Round 11
// baseline (107.106 us; speedup 1.0000x reference)
//
#include <hip/hip_runtime.h>

#define LN 1024
#define FF 128
#define HH 128
#define CC 10
#define DD 34314
#define OFF_W0 0
#define OFF_B0 16384
#define OFF_W1 16512
#define OFF_B1 32896
#define OFF_W2 33024
#define OFF_B2 34304

__global__ void init_delta(float* delta) { *delta = 0.f; }

__device__ __forceinline__ float invmut(const float* h, int node, int par) {
    return 1.f / fmaxf(fabsf(h[node] - h[par]), 1e-7f);
}
__device__ __forceinline__ float l1q(const float4 w) {
    return fabsf(w.x) + fabsf(w.y) + fabsf(w.z) + fabsf(w.w);
}

// One block = one level-8 subtree (4 leaves), 1024 threads, 256 blocks.
// 15 row-streams: R[0..8] = level-8 ancestor .. root, R[9..10] = level-9 pair,
// R[11..14] = 4 leaves. Identical to R10 except layer-0/1 stream loads are
// float4 (dwordx4): halves VMEM instruction count per byte -> 2x bytes in
// flight at the same vmcnt queue depth. Odd-node rows are 8-aligned; gfx950
// unaligned-access-mode handles 8-aligned dwordx4 (validated by absmax).
__global__ __launch_bounds__(1024, 4)
__attribute__((amdgpu_waves_per_eu(4, 4)))
void fused_kernel(const float* __restrict__ W,
                  const float* __restrict__ x,
                  const float* __restrict__ heights,
                  float* __restrict__ out,
                  float* __restrict__ delta_out) {
    const int bid  = blockIdx.x;
    const int m    = ((bid & 7) << 5) | (bid >> 3);   // XCD-chunked bijection (256 = 8 XCD * 32)
    const int tid  = threadIdx.x;
    const int lane = tid & 63;
    const int wv   = tid >> 6;          // 0..15
    const int fhalf = lane >> 5;        // 0..1 : which f-row of the pair
    const int c4    = lane & 31;        // float4 column index (cols 4*c4 .. 4*c4+3)

    int path[9];
    {
        int n = 255 + m;
#pragma unroll
        for (int k = 0; k < 9; ++k) { path[k] = n; n = (n - 1) >> 1; }
    }
    const float* R[15];
#pragma unroll
    for (int k = 0; k < 9; ++k) R[k] = W + (size_t)path[k] * DD;
    const int n9a = 511 + 2 * m, n9b = n9a + 1;
    R[9]  = W + (size_t)n9a * DD;
    R[10] = W + (size_t)n9b * DD;
#pragma unroll
    for (int q = 0; q < 4; ++q) R[11 + q] = W + (size_t)(1023 + 4 * m + q) * DD;

    float wgt[15];
#pragma unroll
    for (int k = 0; k < 8; ++k)
        wgt[k] = ((m & ((1 << k) - 1)) == 0) ? invmut(heights, path[k], path[k + 1]) : 0.f;
    wgt[8]  = 0.f;                       // root: no l1 term (sum-of-squares instead)
    wgt[9]  = invmut(heights, n9a, path[0]);
    wgt[10] = invmut(heights, n9b, path[0]);
#pragma unroll
    for (int q = 0; q < 4; ++q)
        wgt[11 + q] = invmut(heights, 1023 + 4 * m + q, (q < 2) ? n9a : n9b);
    const float sqmask = (m == 0) ? 1.f : 0.f;

    __shared__ float ins[4][HH];         // current layer input per leaf (2 KB)
    __shared__ float part[4][32][HH];    // matvec partials [leaf][frow][col] (64 KB)
    __shared__ float lgts[4][CC];
    __shared__ float red[16];

    if (tid < 512) { const int q = tid >> 7, t = tid & 127; ins[q][t] = x[(4 * m + q) * FF + t]; }
    if (tid < 4 * CC) ((float*)lgts)[tid] = 0.f;

    float dacc = 0.f, sacc = 0.f;
    __syncthreads();

    // ---------------- layers 0 and 1 (128 -> 128), float4 stream loads ----------------
#pragma unroll
    for (int layer = 0; layer < 2; ++layer) {
        const int offW = layer ? OFF_W1 : OFF_W0;
        const int offB = layer ? OFF_B1 : OFF_B0;
        const float4* S4[15];
#pragma unroll
        for (int r = 0; r < 15; ++r) S4[r] = reinterpret_cast<const float4*>(R[r] + offW);

        float4 yv[4];
#pragma unroll
        for (int q = 0; q < 4; ++q) yv[q] = make_float4(0.f, 0.f, 0.f, 0.f);

#pragma unroll 2
        for (int i = 0; i < 4; ++i) {
            const int f   = (wv << 3) + (i << 1) + fhalf;
            const int idx = (f << 5) + c4;
            float4 e;
            {
                const float4 w = S4[0][idx];
                dacc += l1q(w) * wgt[0];
                e = w;
            }
#pragma unroll
            for (int k = 1; k < 9; ++k) {
                const float4 w = S4[k][idx];
                dacc += l1q(w) * wgt[k];
                if (k == 8) sacc += w.x * w.x + w.y * w.y + w.z * w.z + w.w * w.w;
                e.x += w.x; e.y += w.y; e.z += w.z; e.w += w.w;
            }
            const float4 wa0 = S4[9][idx];
            const float4 wa1 = S4[10][idx];
            dacc += l1q(wa0) * wgt[9] + l1q(wa1) * wgt[10];
#pragma unroll
            for (int q = 0; q < 4; ++q) {
                const float4 wb = S4[11 + q][idx];
                dacc += l1q(wb) * wgt[11 + q];
                const float4 wa = (q < 2) ? wa0 : wa1;
                const float xv = ins[q][f];
                yv[q].x += xv * (e.x + wa.x + wb.x);
                yv[q].y += xv * (e.y + wa.y + wb.y);
                yv[q].z += xv * (e.z + wa.z + wb.z);
                yv[q].w += xv * (e.w + wa.w + wb.w);
            }
        }
#pragma unroll
        for (int q = 0; q < 4; ++q)
            *reinterpret_cast<float4*>(&part[q][(wv << 1) + fhalf][c4 << 2]) = yv[q];
        __syncthreads();

        if (tid < 512) {
            const int q = tid >> 7, col = tid & 127;   // q uniform per wave
            float eb = 0.f;
#pragma unroll
            for (int k = 0; k < 9; ++k) {
                const float v = R[k][offB + col];
                eb += v;
                if (q == 0) { dacc += fabsf(v) * wgt[k]; if (k == 8) sacc += v * v; }
            }
            const float a0 = R[9][offB + col];
            const float a1 = R[10][offB + col];
            if (q == 0) dacc += fabsf(a0) * wgt[9];
            if (q == 2) dacc += fabsf(a1) * wgt[10];
            const float bq = R[11 + q][offB + col];
            dacc += fabsf(bq) * wgt[11 + q];
            float s = eb + ((q < 2) ? a0 : a1) + bq;
#pragma unroll
            for (int w = 0; w < 32; ++w) s += part[q][w][col];
            ins[q][col] = fmaxf(s, 0.f);
        }
        __syncthreads();
    }

    // ---------------- layer 2 (128 -> 10), float2 path (3.7% of traffic) ----------------
    {
        const float2* S2[15];
#pragma unroll
        for (int r = 0; r < 15; ++r) S2[r] = reinterpret_cast<const float2*>(R[r] + OFF_W2);
        if (tid < 640) {                 // 640 float2 = 1280 weights per row
            const int h  = tid / 5;
            const int c0 = (tid - 5 * h) * 2;
            float ex = 0.f, ey = 0.f;
#pragma unroll
            for (int k = 0; k < 9; ++k) {
                const float2 w = S2[k][tid];
                ex += w.x; ey += w.y;
                dacc += (fabsf(w.x) + fabsf(w.y)) * wgt[k];
                if (k == 8) sacc += w.x * w.x + w.y * w.y;
            }
            const float2 wa0 = S2[9][tid];
            const float2 wa1 = S2[10][tid];
            dacc += (fabsf(wa0.x) + fabsf(wa0.y)) * wgt[9];
            dacc += (fabsf(wa1.x) + fabsf(wa1.y)) * wgt[10];
#pragma unroll
            for (int q = 0; q < 4; ++q) {
                const float2 wb = S2[11 + q][tid];
                dacc += (fabsf(wb.x) + fabsf(wb.y)) * wgt[11 + q];
                const float2 wa = (q < 2) ? wa0 : wa1;
                const float hv = ins[q][h];
                atomicAdd(&lgts[q][c0],     hv * (ex + wa.x + wb.x));
                atomicAdd(&lgts[q][c0 + 1], hv * (ey + wa.y + wb.y));
            }
        }
        __syncthreads();
        if (tid < CC) {
            float eb = 0.f;
#pragma unroll
            for (int k = 0; k < 9; ++k) {
                const float v = R[k][OFF_B2 + tid];
                eb += v;
                dacc += fabsf(v) * wgt[k];
                if (k == 8) sacc += v * v;
            }
            const float a0 = R[9][OFF_B2 + tid];
            const float a1 = R[10][OFF_B2 + tid];
            dacc += fabsf(a0) * wgt[9] + fabsf(a1) * wgt[10];
#pragma unroll
            for (int q = 0; q < 4; ++q) {
                const float bq = R[11 + q][OFF_B2 + tid];
                dacc += fabsf(bq) * wgt[11 + q];
                lgts[q][tid] += eb + ((q < 2) ? a0 : a1) + bq;
            }
        }
        __syncthreads();
    }

    // ---------------- softmax (one thread per leaf) ----------------
    if (tid < 4) {
        const int q = tid;
        float mx = lgts[q][0];
#pragma unroll
        for (int c = 1; c < CC; ++c) mx = fmaxf(mx, lgts[q][c]);
        float e[CC], s = 0.f;
#pragma unroll
        for (int c = 0; c < CC; ++c) { e[c] = expf(lgts[q][c] - mx); s += e[c]; }
        const float inv = 1.f / s;
#pragma unroll
        for (int c = 0; c < CC; ++c) out[(4 * m + q) * CC + c] = e[c] * inv;
    }

    // ---------------- delta reduce: one weighted accumulator ----------------
    float v = dacc + sacc * sqmask;
    for (int o = 32; o > 0; o >>= 1) v += __shfl_down(v, o);
    if (lane == 0) red[wv] = v;
    __syncthreads();
    if (tid == 0) {
        float s = 0.f;
#pragma unroll
        for (int w = 0; w < 16; ++w) s += red[w];
        atomicAdd(delta_out, s);
    }
}

extern "C" void kernel_launch(void* const* d_in, const int* in_sizes, int n_in,
                              void* d_out, int out_size, void* d_ws, size_t ws_size,
                              hipStream_t stream) {
    const float* x       = (const float*)d_in[0];   // (1024, 128)
    const float* W       = (const float*)d_in[1];   // (2047, 34314)
    const float* heights = (const float*)d_in[2];   // (2047,)

    float* out   = (float*)d_out;
    float* delta = (float*)d_out + LN * CC;

    init_delta<<<1, 1, 0, stream>>>(delta);
    fused_kernel<<<256, 1024, 0, stream>>>(W, x, heights, out, delta);
}